// Round 1
// baseline (470.501 us; speedup 1.0000x reference)
//
#include <hip/hip_runtime.h>
#include <math.h>

#define NL 24
#define BB 16
#define HH 32
#define DD 64
#define EE 2048
#define TSH 32
#define NB 5
#define BE (BB*EE)            /* 32768  */
#define STATE_N (NL*BB*EE)    /* 786432 */
#define SM_N (NL*BB*HH*DD*DD) /* 50331648 */
#define GN_EPS 1e-3f

// =====================================================================
// K1: state passthrough copy + bias inits + fused branch chain
//     (hdn -> ts -> proj all in LDS; also writes gx for the gate GEMV)
// grid = 768 copy + 256 bias + 80 branch = 1104 blocks x 256
// =====================================================================
__global__ __launch_bounds__(256) void k_head(
    const float4* __restrict__ state4, const float4* __restrict__ inputs4,
    float4* __restrict__ out_state4,
    float* __restrict__ out_tm, float* __restrict__ g,
    const float* __restrict__ out_b, const float* __restrict__ gate_b,
    const float* __restrict__ inputs, const float* __restrict__ state,
    const float* __restrict__ mus, const float* __restrict__ Aw,
    const float* __restrict__ Ab, const float* __restrict__ lambdas,
    const float* __restrict__ Bw, const float* __restrict__ Bb,
    const float* __restrict__ MW, const float* __restrict__ Mb,
    const float* __restrict__ gate_mu, float* __restrict__ proj,
    float* __restrict__ gx, const int* __restrict__ lid_p)
{
    int blk = blockIdx.x, tid = threadIdx.x;
    int lid = *lid_p;
    if (blk < 768) {                            // 196608 float4 state copy
        int i = blk * 256 + tid;
        int lo = lid * (BE / 4);
        float4 v = (i >= lo && i < lo + BE / 4) ? inputs4[i - lo] : state4[i];
        out_state4[i] = v;
        return;
    }
    if (blk < 1024) {                           // 65536 bias inits
        int idx = (blk - 768) * 256 + tid;
        if (idx < BE) out_tm[idx] = out_b[idx & (EE - 1)];
        else g[idx - BE] = gate_b[(idx - BE) & (EE - 1)];
        return;
    }
    // ---- branch chain: one block per (s,b) ----
    int sb = blk - 1024;
    int s = sb / BB, b = sb % BB;
    __shared__ float xs[EE], dsh[EE], lis[EE], tsl[EE];   // 32 KB
    __shared__ float red[TSH][9];
    __shared__ float hdnl[TSH];
    const float* x  = inputs + b * EE;
    const float* lx = state + lid * BE + b * EE;
    const float* mu = mus + s * EE;
    for (int e = tid; e < EE; e += 256) {
        float xv = x[e], lxv = lx[e];
        float d = xv - lxv;
        xs[e] = xv; dsh[e] = d;
        lis[e] = xv + d * mu[e];
        if (s == 0) {
            float gm = gate_mu[e];
            gx[b * EE + e] = xv * gm + lxv * (1.f - gm);
        }
    }
    __syncthreads();
    {   // hdn partials: 8 parts x 256 elems, 32 h-lanes each
        int h = tid & 31, part = tid >> 5;
        const float* A = Aw + s * EE * TSH;
        float acc = 0.f;
        int e0 = part * 256;
        #pragma unroll 8
        for (int e = e0; e < e0 + 256; ++e) acc += lis[e] * A[e * TSH + h];
        red[h][part] = acc;
    }
    __syncthreads();
    if (tid < TSH) {
        float sum = Ab[s * TSH + tid];
        #pragma unroll
        for (int p = 0; p < 8; ++p) sum += red[tid][p];
        hdnl[tid] = tanhf(sum);
    }
    __syncthreads();
    for (int e = tid; e < EE; e += 256) {       // ts (kept in LDS)
        const float* Bp = Bw + s * TSH * EE + e;
        float acc = Bb[s * EE + e] + lambdas[s * EE + e];
        #pragma unroll
        for (int h2 = 0; h2 < TSH; ++h2) acc += hdnl[h2] * Bp[h2 * EE];
        tsl[e] = acc * dsh[e] + xs[e];
    }
    __syncthreads();
    for (int o = tid; o < EE; o += 256) {       // per-head dense -> proj
        int h2 = o >> 6, e = o & 63;
        const float* M = MW + (s * HH + h2) * DD * DD;
        const float* t = tsl + h2 * DD;
        float acc = Mb[(s * HH + h2) * DD + e];
        #pragma unroll 8
        for (int d = 0; d < DD; ++d) acc += t[d] * M[d * DD + e];
        proj[(s * BB + b) * EE + o] = acc;
    }
}

// =====================================================================
// GEMV block: out[b,e] += sum_k A[b,k]*W[k,e]; A tile staged in LDS
// (optionally fused with *silu(G)).  blk in [0,256): 8 e-tiles x 32 k-chunks
// =====================================================================
template <bool SILU>
__device__ __forceinline__ void mm_block(
    int blk, const float* __restrict__ Arows, const float* __restrict__ Grows,
    const float* __restrict__ W, float* __restrict__ out)
{
    int tid = threadIdx.x;
    int et = blk & 7, kc = blk >> 3;
    int e = et * 256 + tid;
    int k0 = kc * 64;
    __shared__ float As[BB][64];
    for (int i = tid; i < BB * 64; i += 256) {
        int b = i >> 6, kk = i & 63;
        float av = Arows[b * EE + k0 + kk];
        if constexpr (SILU) {
            float gv = Grows[b * EE + k0 + kk];
            av *= gv / (1.f + expf(-gv));
        }
        As[b][kk] = av;
    }
    __syncthreads();
    float acc[BB];
    #pragma unroll
    for (int b = 0; b < BB; ++b) acc[b] = 0.f;
    #pragma unroll 8
    for (int kk = 0; kk < 64; ++kk) {
        float wv = W[(k0 + kk) * EE + e];
        #pragma unroll
        for (int b = 0; b < BB; ++b) acc[b] += As[b][kk] * wv;
    }
    #pragma unroll
    for (int b = 0; b < BB; ++b) atomicAdd(&out[b * EE + e], acc[b]);
}

// =====================================================================
// K2: gate GEMV (256 blocks) + RWKV lid-layer update + groupnorm (512)
// grid = 768 blocks x 256.  a_out stores NORMED only (silu moved to K3).
// =====================================================================
__global__ __launch_bounds__(256) void k_mid(
    const float* __restrict__ gx, const float* __restrict__ gate_W,
    float* __restrict__ g,
    const float4* __restrict__ sm4, float4* __restrict__ out_sm4,
    const float* __restrict__ proj,
    const float* __restrict__ gn_gamma, const float* __restrict__ gn_beta,
    float* __restrict__ a_out, const int* __restrict__ lid_p)
{
    int blk = blockIdx.x, tid = threadIdx.x;
    if (blk < 256) { mm_block<false>(blk, gx, nullptr, gate_W, g); return; }
    int lid = *lid_p;
    int r = blk - 256;                          // [0, 512): (b,h)
    int b = r / HH, h = r % HH;
    int base4 = (lid * BB * HH + r) * (DD * DD / 4);
    int j = tid & 63, q = tid >> 6;
    const float* P = proj + (b * HH + h) * DD + j;
    float kv   = P[0 * BE];
    float rv   = P[1 * BE];
    float wraw = P[2 * BE];
    float vv   = P[3 * BE];
    float uv   = P[4 * BE];
    float wv = expf(-expf(wraw));
    float vr = vv * rv;
    #pragma unroll
    for (int o = 32; o; o >>= 1) vr += __shfl_xor(vr, o);
    __shared__ float rw[DD];
    const float* S = (const float*)(sm4 + base4);
    float* NS = (float*)(out_sm4 + base4);
    for (int ii = 0; ii < 16; ii += 4) {
        int i0 = q * 16 + ii;
        float sv[4], kk[4], ww[4], uu[4], pp[4];
        #pragma unroll
        for (int t = 0; t < 4; ++t) {
            sv[t] = S[(i0 + t) * DD + j];
            kk[t] = __shfl(kv, i0 + t);
            ww[t] = __shfl(wv, i0 + t);
            uu[t] = __shfl(uv, i0 + t);
        }
        #pragma unroll
        for (int t = 0; t < 4; ++t) {
            NS[(i0 + t) * DD + j] = ww[t] * sv[t] + kk[t] * vv;
            pp[t] = sv[t] * rv;
        }
        #pragma unroll
        for (int o = 32; o; o >>= 1) {
            #pragma unroll
            for (int t = 0; t < 4; ++t) pp[t] += __shfl_xor(pp[t], o);
        }
        if (j == 0) {
            #pragma unroll
            for (int t = 0; t < 4; ++t) rw[i0 + t] = kk[t] * uu[t] * vr + pp[t];
        }
    }
    __syncthreads();
    if (tid < DD) {
        float xv = rw[tid];
        float m = xv;
        #pragma unroll
        for (int o = 32; o; o >>= 1) m += __shfl_xor(m, o);
        m *= (1.f / 64.f);
        float d = xv - m;
        float var = d * d;
        #pragma unroll
        for (int o = 32; o; o >>= 1) var += __shfl_xor(var, o);
        var *= (1.f / 64.f);
        float normed = d * rsqrtf(var + GN_EPS);
        int e = h * DD + tid;
        a_out[b * EE + e] = normed * gn_gamma[e] + gn_beta[e];
    }
}

// =====================================================================
// K3: output GEMV with fused silu-gating (256 blocks, dispatched first)
//     + state_matrix passthrough copy of the 23 untouched layers (11776)
// grid = 12032 blocks x 256
// =====================================================================
__global__ __launch_bounds__(256) void k_tail(
    const float* __restrict__ a, const float* __restrict__ g,
    const float* __restrict__ out_W, float* __restrict__ out_tm,
    const float4* __restrict__ sm4, float4* __restrict__ out_sm4,
    const int* __restrict__ lid_p)
{
    int blk = blockIdx.x, tid = threadIdx.x;
    if (blk < 256) { mm_block<true>(blk, a, g, out_W, out_tm); return; }
    int lid = *lid_p;
    int c = blk - 256;                          // [0, 11776) head-chunks
    int l = c >> 9;                             // /512 chunks-per-layer
    int rr = c & 511;
    int ls = l + (l >= lid);
    const float4* src = sm4 + ((long)ls * 512 + rr) * 1024;
    float4* dst = out_sm4 + ((long)ls * 512 + rr) * 1024;
    #pragma unroll
    for (int p = 0; p < 4; ++p) dst[p * 256 + tid] = src[p * 256 + tid];
}

extern "C" void kernel_launch(void* const* d_in, const int* in_sizes, int n_in,
                              void* d_out, int out_size, void* d_ws, size_t ws_size,
                              hipStream_t stream) {
    const float* inputs   = (const float*)d_in[0];
    const float* state    = (const float*)d_in[1];
    const float* sm       = (const float*)d_in[2];
    const float* mus      = (const float*)d_in[3];
    const float* lambdas  = (const float*)d_in[4];
    const float* Aw       = (const float*)d_in[5];
    const float* Ab       = (const float*)d_in[6];
    const float* Bw       = (const float*)d_in[7];
    const float* Bb       = (const float*)d_in[8];
    const float* MW       = (const float*)d_in[9];
    const float* Mb       = (const float*)d_in[10];
    const float* gate_mu  = (const float*)d_in[11];
    const float* gate_W   = (const float*)d_in[12];
    const float* gate_b   = (const float*)d_in[13];
    const float* gn_gamma = (const float*)d_in[14];
    const float* gn_beta  = (const float*)d_in[15];
    const float* out_W    = (const float*)d_in[16];
    const float* out_b    = (const float*)d_in[17];
    const int*   lid      = (const int*)d_in[18];

    float* out_tm    = (float*)d_out;
    float* out_state = out_tm + BE;
    float* out_sm    = out_state + STATE_N;

    float* ws   = (float*)d_ws;
    float* proj = ws;                       // NB*BE
    float* gx   = proj + NB * BE;           // BE
    float* g    = gx + BE;                  // BE
    float* a    = g + BE;                   // BE

    k_head<<<1104, 256, 0, stream>>>((const float4*)state, (const float4*)inputs,
                                     (float4*)out_state, out_tm, g, out_b, gate_b,
                                     inputs, state, mus, Aw, Ab, lambdas, Bw, Bb,
                                     MW, Mb, gate_mu, proj, gx, lid);
    k_mid<<<768, 256, 0, stream>>>(gx, gate_W, g, (const float4*)sm, (float4*)out_sm,
                                   proj, gn_gamma, gn_beta, a, lid);
    k_tail<<<12032, 256, 0, stream>>>(a, g, out_W, out_tm,
                                      (const float4*)sm, (float4*)out_sm, lid);
}

// Round 3
// 442.509 us; speedup vs baseline: 1.0633x; 1.0633x over previous
//
#include <hip/hip_runtime.h>
#include <math.h>

#define NL 24
#define BB 16
#define HH 32
#define DD 64
#define EE 2048
#define TSH 32
#define NB 5
#define BE (BB*EE)            /* 32768  */
#define STATE_N (NL*BB*EE)    /* 786432 */
#define GN_EPS 1e-3f

/* 23 non-lid layers x 512 chunks of 16KB = 11776 sm passthrough chunks */
#define NCH 11776
#define C1 2400
#define C2 2200
#define C3 2400
#define C4 2200
#define C5 1776
#define C6 800

// ---- one 16KB head-chunk of the 23-layer state_matrix passthrough copy ----
__device__ __forceinline__ void sm_chunk(int c, int lid, const float4* __restrict__ sm4,
                                         float4* __restrict__ out4, int tid) {
    int l = c >> 9, rr = c & 511;
    int ls = l + (l >= lid);
    const float4* src = sm4 + (long)(ls * 512 + rr) * 1024;
    float4*       dst = out4 + (long)(ls * 512 + rr) * 1024;
    #pragma unroll
    for (int p = 0; p < 4; ++p) dst[p * 256 + tid] = src[p * 256 + tid];
}

// =====================================================================
// K1: hdn (80 blocks) + state copy (768) + bias inits (256) + sm copy C1
// =====================================================================
__global__ __launch_bounds__(256) void k1_hdn(
    const float* __restrict__ inputs, const float* __restrict__ state,
    const float* __restrict__ mus, const float* __restrict__ Aw,
    const float* __restrict__ Ab, float* __restrict__ hdn,
    const float4* __restrict__ state4, const float4* __restrict__ inputs4,
    float4* __restrict__ out_state4, float* __restrict__ out_tm,
    float* __restrict__ g, const float* __restrict__ out_b,
    const float* __restrict__ gate_b,
    const float4* __restrict__ sm4, float4* __restrict__ out_sm4,
    const int* __restrict__ lid_p)
{
    int blk = blockIdx.x, tid = threadIdx.x;
    int lid = *lid_p;
    if (blk >= 1104) {                          // sm copy chunks [0, C1)
        sm_chunk(blk - 1104, lid, sm4, out_sm4, tid);
        return;
    }
    if (blk >= 848) {                           // bias inits (65536 elems)
        int idx = (blk - 848) * 256 + tid;
        if (idx < BE) out_tm[idx] = out_b[idx & (EE - 1)];
        else g[idx - BE] = gate_b[(idx - BE) & (EE - 1)];
        return;
    }
    if (blk >= 80) {                            // state copy (196608 float4)
        int i = (blk - 80) * 256 + tid;
        int lo = lid * (BE / 4);
        float4 v = (i >= lo && i < lo + BE / 4) ? inputs4[i - lo] : state4[i];
        out_state4[i] = v;
        return;
    }
    // ---- hdn for one (s,b) ----
    int s = blk / BB, b = blk % BB;
    __shared__ float li[EE];
    const float* x  = inputs + b * EE;
    const float* lx = state + lid * BE + b * EE;
    const float* mu = mus + s * EE;
    for (int e = tid; e < EE; e += 256) {
        float xv = x[e];
        li[e] = xv + (xv - lx[e]) * mu[e];
    }
    __syncthreads();
    int h = tid & 31, part = tid >> 5;          // 8 parts x 256 elems
    const float* A = Aw + s * EE * TSH;
    float acc = 0.f;
    int e0 = part * 256;
    #pragma unroll 8
    for (int e = e0; e < e0 + 256; ++e) acc += li[e] * A[e * TSH + h];
    __shared__ float red[32][9];
    red[h][part] = acc;
    __syncthreads();
    if (tid < 32) {
        float sum = Ab[s * TSH + tid];
        #pragma unroll
        for (int p = 0; p < 8; ++p) sum += red[tid][p];
        hdn[(s * BB + b) * TSH + tid] = tanhf(sum);
    }
}

// =====================================================================
// K2: ts = (hdn@Bw + Bb + lambda)*diff + x ; gx   (640 blocks) + sm copy C2
// =====================================================================
__global__ __launch_bounds__(256) void k2_ts(
    const float* __restrict__ inputs, const float* __restrict__ state,
    const float* __restrict__ lambdas, const float* __restrict__ Bw,
    const float* __restrict__ Bb, const float* __restrict__ hdn,
    const float* __restrict__ gate_mu, float* __restrict__ ts,
    float* __restrict__ gx,
    const float4* __restrict__ sm4, float4* __restrict__ out_sm4,
    const int* __restrict__ lid_p)
{
    int blk = blockIdx.x, tid = threadIdx.x;
    int lid = *lid_p;
    if (blk >= 640) {                           // sm copy chunks [C1, C1+C2)
        sm_chunk(C1 + blk - 640, lid, sm4, out_sm4, tid);
        return;
    }
    int idx = blk * 256 + tid;                  // NB*BE
    int s = idx / BE, r = idx % BE;
    int b = r / EE, e = r % EE;
    const float* hp = hdn + (s * BB + b) * TSH;
    const float* Bp = Bw + s * TSH * EE + e;
    float acc = Bb[s * EE + e] + lambdas[s * EE + e];
    #pragma unroll
    for (int h = 0; h < TSH; ++h) acc += hp[h] * Bp[h * EE];
    float xv = inputs[r];
    float lxv = state[lid * BE + r];
    ts[idx] = acc * (xv - lxv) + xv;
    if (s == 0) {
        float gm = gate_mu[e];
        gx[r] = xv * gm + lxv * (1.f - gm);
    }
}

// =====================================================================
// K3: per-head dense proj (640 blocks, 4 heads/block) + sm copy C3
// =====================================================================
__global__ __launch_bounds__(256) void k3_proj(
    const float* __restrict__ ts, const float* __restrict__ MW,
    const float* __restrict__ Mb, float* __restrict__ proj,
    const float4* __restrict__ sm4, float4* __restrict__ out_sm4,
    const int* __restrict__ lid_p)
{
    int bi = blockIdx.x, tid = threadIdx.x;
    if (bi >= 640) {                            // sm copy chunks [C1+C2, ...)
        int lid = *lid_p;
        sm_chunk(C1 + C2 + bi - 640, lid, sm4, out_sm4, tid);
        return;
    }
    int s = bi / (BB * 8);
    int r = bi % (BB * 8);
    int b = r / 8, hg = r % 8;
    int q = tid >> 6, e = tid & 63;
    int h = hg * 4 + q;
    __shared__ float tl[4][DD];
    tl[q][e] = ts[((s * BB + b) * HH + h) * DD + e];
    __syncthreads();
    const float* M = MW + (s * HH + h) * DD * DD;
    float acc = Mb[(s * HH + h) * DD + e];
    #pragma unroll 8
    for (int d = 0; d < DD; ++d) acc += tl[q][d] * M[d * DD + e];
    proj[((s * BB + b) * HH + h) * DD + e] = acc;
}

// ---- GEMV block (256 thr): out[b,e] += sum_k A[b,k]*W[k,e]; LDS-staged A ----
// t in [0,256): 8 e-tiles(256) x 32 k-chunks(64); optional silu(G) gating
template <bool SILU>
__device__ __forceinline__ void mm_block(
    int t, const float* __restrict__ Arows, const float* __restrict__ Grows,
    const float* __restrict__ W, float* __restrict__ out, int tid)
{
    int et = t & 7, kc = t >> 3;
    int e = et * 256 + tid;
    int k0 = kc * 64;
    __shared__ float As[BB][64];
    for (int i = tid; i < BB * 64; i += 256) {
        int b = i >> 6, kk = i & 63;
        float av = Arows[b * EE + k0 + kk];
        if constexpr (SILU) {
            float gv = Grows[b * EE + k0 + kk];
            av *= gv / (1.f + expf(-gv));
        }
        As[b][kk] = av;
    }
    __syncthreads();
    float acc[BB];
    #pragma unroll
    for (int b = 0; b < BB; ++b) acc[b] = 0.f;
    #pragma unroll 8
    for (int kk = 0; kk < 64; ++kk) {
        float wv = W[(k0 + kk) * EE + e];
        #pragma unroll
        for (int b = 0; b < BB; ++b) acc[b] += As[b][kk] * wv;
    }
    #pragma unroll
    for (int b = 0; b < BB; ++b) atomicAdd(&out[b * EE + e], acc[b]);
}

// =====================================================================
// K4: gate GEMV (256 blocks) + sm copy C4
// =====================================================================
__global__ __launch_bounds__(256) void k4_gate(
    const float* __restrict__ gx, const float* __restrict__ gate_W,
    float* __restrict__ g,
    const float4* __restrict__ sm4, float4* __restrict__ out_sm4,
    const int* __restrict__ lid_p)
{
    int blk = blockIdx.x, tid = threadIdx.x;
    if (blk < 256) { mm_block<false>(blk, gx, nullptr, gate_W, g, tid); return; }
    int lid = *lid_p;
    sm_chunk(C1 + C2 + C3 + blk - 256, lid, sm4, out_sm4, tid);
}

// =====================================================================
// K5: RWKV lid-layer update + groupnorm (512 blocks) + sm copy C5
// =====================================================================
__global__ __launch_bounds__(256) void k5_rwkv(
    const float4* __restrict__ sm4, float4* __restrict__ out_sm4,
    const float* __restrict__ proj,
    const float* __restrict__ gn_gamma, const float* __restrict__ gn_beta,
    float* __restrict__ a_out, const int* __restrict__ lid_p)
{
    int blk = blockIdx.x, tid = threadIdx.x;
    int lid = *lid_p;
    if (blk >= 512) {
        sm_chunk(C1 + C2 + C3 + C4 + blk - 512, lid, sm4, out_sm4, tid);
        return;
    }
    int b = blk / HH, h = blk % HH;
    long base4 = (long)(lid * BB * HH + blk) * (DD * DD / 4);
    int j = tid & 63, q = tid >> 6;
    const float* P = proj + (b * HH + h) * DD + j;
    float kv   = P[0 * BE];
    float rv   = P[1 * BE];
    float wraw = P[2 * BE];
    float vv   = P[3 * BE];
    float uv   = P[4 * BE];
    float wv = expf(-expf(wraw));
    float vr = vv * rv;
    #pragma unroll
    for (int o = 32; o; o >>= 1) vr += __shfl_xor(vr, o);
    __shared__ float rw[DD];
    const float* S = (const float*)(sm4 + base4);
    float* NS = (float*)(out_sm4 + base4);
    for (int ii = 0; ii < 16; ii += 4) {
        int i0 = q * 16 + ii;
        float sv[4], kk[4], ww[4], uu[4], pp[4];
        #pragma unroll
        for (int t = 0; t < 4; ++t) {
            sv[t] = S[(i0 + t) * DD + j];
            kk[t] = __shfl(kv, i0 + t);
            ww[t] = __shfl(wv, i0 + t);
            uu[t] = __shfl(uv, i0 + t);
        }
        #pragma unroll
        for (int t = 0; t < 4; ++t) {
            NS[(i0 + t) * DD + j] = ww[t] * sv[t] + kk[t] * vv;
            pp[t] = sv[t] * rv;
        }
        #pragma unroll
        for (int o = 32; o; o >>= 1) {
            #pragma unroll
            for (int t = 0; t < 4; ++t) pp[t] += __shfl_xor(pp[t], o);
        }
        if (j == 0) {
            #pragma unroll
            for (int t = 0; t < 4; ++t) rw[i0 + t] = kk[t] * uu[t] * vr + pp[t];
        }
    }
    __syncthreads();
    if (tid < DD) {
        float xv = rw[tid];
        float m = xv;
        #pragma unroll
        for (int o = 32; o; o >>= 1) m += __shfl_xor(m, o);
        m *= (1.f / 64.f);
        float d = xv - m;
        float var = d * d;
        #pragma unroll
        for (int o = 32; o; o >>= 1) var += __shfl_xor(var, o);
        var *= (1.f / 64.f);
        float normed = d * rsqrtf(var + GN_EPS);
        int e = h * DD + tid;
        a_out[b * EE + e] = normed * gn_gamma[e] + gn_beta[e];
    }
}

// =====================================================================
// K6: out GEMV with fused silu gating (256 blocks) + sm copy C6 (last 800)
// =====================================================================
__global__ __launch_bounds__(256) void k6_out(
    const float* __restrict__ a, const float* __restrict__ g,
    const float* __restrict__ out_W, float* __restrict__ out_tm,
    const float4* __restrict__ sm4, float4* __restrict__ out_sm4,
    const int* __restrict__ lid_p)
{
    int blk = blockIdx.x, tid = threadIdx.x;
    if (blk < 256) { mm_block<true>(blk, a, g, out_W, out_tm, tid); return; }
    int lid = *lid_p;
    sm_chunk(C1 + C2 + C3 + C4 + C5 + blk - 256, lid, sm4, out_sm4, tid);
}

extern "C" void kernel_launch(void* const* d_in, const int* in_sizes, int n_in,
                              void* d_out, int out_size, void* d_ws, size_t ws_size,
                              hipStream_t stream) {
    const float* inputs   = (const float*)d_in[0];
    const float* state    = (const float*)d_in[1];
    const float* sm       = (const float*)d_in[2];
    const float* mus      = (const float*)d_in[3];
    const float* lambdas  = (const float*)d_in[4];
    const float* Aw       = (const float*)d_in[5];
    const float* Ab       = (const float*)d_in[6];
    const float* Bw       = (const float*)d_in[7];
    const float* Bb       = (const float*)d_in[8];
    const float* MW       = (const float*)d_in[9];
    const float* Mb       = (const float*)d_in[10];
    const float* gate_mu  = (const float*)d_in[11];
    const float* gate_W   = (const float*)d_in[12];
    const float* gate_b   = (const float*)d_in[13];
    const float* gn_gamma = (const float*)d_in[14];
    const float* gn_beta  = (const float*)d_in[15];
    const float* out_W    = (const float*)d_in[16];
    const float* out_b    = (const float*)d_in[17];
    const int*   lid      = (const int*)d_in[18];

    float* out_tm    = (float*)d_out;
    float* out_state = out_tm + BE;
    float* out_sm    = out_state + STATE_N;

    float* ws   = (float*)d_ws;
    float* ts   = ws;                       // NB*BE
    float* proj = ts + NB * BE;             // NB*BE
    float* hdn  = proj + NB * BE;           // NB*BB*TSH
    float* gx   = hdn + NB * BB * TSH;      // BE
    float* g    = gx + BE;                  // BE
    float* a    = g + BE;                   // BE

    k1_hdn<<<1104 + C1, 256, 0, stream>>>(inputs, state, mus, Aw, Ab, hdn,
        (const float4*)state, (const float4*)inputs, (float4*)out_state,
        out_tm, g, out_b, gate_b, (const float4*)sm, (float4*)out_sm, lid);
    k2_ts<<<640 + C2, 256, 0, stream>>>(inputs, state, lambdas, Bw, Bb, hdn,
        gate_mu, ts, gx, (const float4*)sm, (float4*)out_sm, lid);
    k3_proj<<<640 + C3, 256, 0, stream>>>(ts, MW, Mb, proj,
        (const float4*)sm, (float4*)out_sm, lid);
    k4_gate<<<256 + C4, 256, 0, stream>>>(gx, gate_W, g,
        (const float4*)sm, (float4*)out_sm, lid);
    k5_rwkv<<<512 + C5, 256, 0, stream>>>((const float4*)sm, (float4*)out_sm,
        proj, gn_gamma, gn_beta, a, lid);
    k6_out<<<256 + C6, 256, 0, stream>>>(a, g, out_W, out_tm,
        (const float4*)sm, (float4*)out_sm, lid);
}

// Round 4
// 436.901 us; speedup vs baseline: 1.0769x; 1.0128x over previous
//
#include <hip/hip_runtime.h>
#include <math.h>

#define NL 24
#define BB 16
#define HH 32
#define DD 64
#define EE 2048
#define TSH 32
#define NB 5
#define BE (BB*EE)            /* 32768  */
#define STATE_N (NL*BB*EE)    /* 786432 */
#define GN_EPS 1e-3f

/* 23 non-lid layers x 512 chunks of 16KB = 11776 sm passthrough chunks */
#define NCH 11776
#define C1 2700
#define C2 2500
#define C3 2100
#define C4 2400
#define C5 2076

typedef float nt4 __attribute__((ext_vector_type(4)));

// ---- one 16KB head-chunk of the 23-layer sm passthrough copy (nontemporal) ----
__device__ __forceinline__ void sm_chunk(int c, int lid, const nt4* __restrict__ sm4,
                                         nt4* __restrict__ out4, int tid) {
    int l = c >> 9, rr = c & 511;
    int ls = l + (l >= lid);
    const nt4* src = sm4 + (long)(ls * 512 + rr) * 1024;
    nt4*       dst = out4 + (long)(ls * 512 + rr) * 1024;
    #pragma unroll
    for (int p = 0; p < 4; ++p) {
        nt4 v = __builtin_nontemporal_load(&src[p * 256 + tid]);
        __builtin_nontemporal_store(v, &dst[p * 256 + tid]);
    }
}

// =====================================================================
// K1: hdn (80) + state copy (768) + aux bias/gx (384) + sm chunks C1
// =====================================================================
__global__ __launch_bounds__(256) void k1_hdn(
    const float* __restrict__ inputs, const float* __restrict__ state,
    const float* __restrict__ mus, const float* __restrict__ Aw,
    const float* __restrict__ Ab, float* __restrict__ hdn,
    const nt4* __restrict__ state4, const float4* __restrict__ inputs4,
    nt4* __restrict__ out_state4, float* __restrict__ out_tm,
    float* __restrict__ g, const float* __restrict__ out_b,
    const float* __restrict__ gate_b, const float* __restrict__ gate_mu,
    float* __restrict__ gx,
    const nt4* __restrict__ sm4, nt4* __restrict__ out_sm4,
    const int* __restrict__ lid_p)
{
    int blk = blockIdx.x, tid = threadIdx.x;
    int lid = *lid_p;
    if (blk >= 1232) {                          // sm copy chunks [0, C1)
        sm_chunk(blk - 1232, lid, sm4, out_sm4, tid);
        return;
    }
    if (blk >= 848) {                           // aux: out_tm/g bias + gx (98304)
        int idx = (blk - 848) * 256 + tid;
        if (idx < BE) out_tm[idx] = out_b[idx & (EE - 1)];
        else if (idx < 2 * BE) g[idx - BE] = gate_b[(idx - BE) & (EE - 1)];
        else {
            int r = idx - 2 * BE;
            float xv = inputs[r];
            float lxv = state[lid * BE + r];
            float gm = gate_mu[r & (EE - 1)];
            gx[r] = xv * gm + lxv * (1.f - gm);
        }
        return;
    }
    if (blk >= 80) {                            // state copy (196608 float4)
        int i = (blk - 80) * 256 + tid;
        int lo = lid * (BE / 4);
        if (i >= lo && i < lo + BE / 4) {
            float4 v = inputs4[i - lo];
            nt4 w = { v.x, v.y, v.z, v.w };
            __builtin_nontemporal_store(w, &out_state4[i]);
        } else {
            nt4 v = __builtin_nontemporal_load(&state4[i]);
            __builtin_nontemporal_store(v, &out_state4[i]);
        }
        return;
    }
    // ---- hdn for one (s,b) ----
    int s = blk / BB, b = blk % BB;
    __shared__ float li[EE];
    const float* x  = inputs + b * EE;
    const float* lx = state + lid * BE + b * EE;
    const float* mu = mus + s * EE;
    for (int e = tid; e < EE; e += 256) {
        float xv = x[e];
        li[e] = xv + (xv - lx[e]) * mu[e];
    }
    __syncthreads();
    int h = tid & 31, part = tid >> 5;          // 8 parts x 256 elems
    const float* A = Aw + s * EE * TSH;
    float acc = 0.f;
    int e0 = part * 256;
    #pragma unroll 8
    for (int e = e0; e < e0 + 256; ++e) acc += li[e] * A[e * TSH + h];
    __shared__ float red[32][9];
    red[h][part] = acc;
    __syncthreads();
    if (tid < 32) {
        float sum = Ab[s * TSH + tid];
        #pragma unroll
        for (int p = 0; p < 8; ++p) sum += red[tid][p];
        hdn[(s * BB + b) * TSH + tid] = tanhf(sum);
    }
}

// =====================================================================
// K2: ts = (hdn@Bw + Bb + lambda)*diff + x  (640 blocks) + sm chunks C2
// =====================================================================
__global__ __launch_bounds__(256) void k2_ts(
    const float* __restrict__ inputs, const float* __restrict__ state,
    const float* __restrict__ lambdas, const float* __restrict__ Bw,
    const float* __restrict__ Bb, const float* __restrict__ hdn,
    float* __restrict__ ts,
    const nt4* __restrict__ sm4, nt4* __restrict__ out_sm4,
    const int* __restrict__ lid_p)
{
    int blk = blockIdx.x, tid = threadIdx.x;
    int lid = *lid_p;
    if (blk >= 640) {                           // sm copy chunks [C1, C1+C2)
        sm_chunk(C1 + blk - 640, lid, sm4, out_sm4, tid);
        return;
    }
    int idx = blk * 256 + tid;                  // NB*BE
    int s = idx / BE, r = idx % BE;
    int b = r / EE, e = r % EE;
    const float* hp = hdn + (s * BB + b) * TSH;
    const float* Bp = Bw + s * TSH * EE + e;
    float acc = Bb[s * EE + e] + lambdas[s * EE + e];
    #pragma unroll
    for (int h = 0; h < TSH; ++h) acc += hp[h] * Bp[h * EE];
    float xv = inputs[r];
    float lxv = state[lid * BE + r];
    ts[idx] = acc * (xv - lxv) + xv;
}

// ---- GEMV block (256 thr): out[b,e] += sum_k A[b,k]*W[k,e]; LDS-staged A ----
template <bool SILU>
__device__ __forceinline__ void mm_block(
    int t, const float* __restrict__ Arows, const float* __restrict__ Grows,
    const float* __restrict__ W, float* __restrict__ out, int tid)
{
    int et = t & 7, kc = t >> 3;
    int e = et * 256 + tid;
    int k0 = kc * 64;
    __shared__ float As[BB][64];
    for (int i = tid; i < BB * 64; i += 256) {
        int b = i >> 6, kk = i & 63;
        float av = Arows[b * EE + k0 + kk];
        if constexpr (SILU) {
            float gv = Grows[b * EE + k0 + kk];
            av *= gv / (1.f + expf(-gv));
        }
        As[b][kk] = av;
    }
    __syncthreads();
    float acc[BB];
    #pragma unroll
    for (int b = 0; b < BB; ++b) acc[b] = 0.f;
    #pragma unroll 8
    for (int kk = 0; kk < 64; ++kk) {
        float wv = W[(k0 + kk) * EE + e];
        #pragma unroll
        for (int b = 0; b < BB; ++b) acc[b] += As[b][kk] * wv;
    }
    #pragma unroll
    for (int b = 0; b < BB; ++b) atomicAdd(&out[b * EE + e], acc[b]);
}

// =====================================================================
// K3: per-head dense proj (640) + gate GEMV (256) + sm chunks C3
// =====================================================================
__global__ __launch_bounds__(256) void k3_proj(
    const float* __restrict__ ts, const float* __restrict__ MW,
    const float* __restrict__ Mb, float* __restrict__ proj,
    const float* __restrict__ gx, const float* __restrict__ gate_W,
    float* __restrict__ g,
    const nt4* __restrict__ sm4, nt4* __restrict__ out_sm4,
    const int* __restrict__ lid_p)
{
    int bi = blockIdx.x, tid = threadIdx.x;
    if (bi >= 896) {                            // sm copy chunks
        int lid = *lid_p;
        sm_chunk(C1 + C2 + bi - 896, lid, sm4, out_sm4, tid);
        return;
    }
    if (bi >= 640) {                            // gate GEMV
        mm_block<false>(bi - 640, gx, nullptr, gate_W, g, tid);
        return;
    }
    int s = bi / (BB * 8);
    int r = bi % (BB * 8);
    int b = r / 8, hg = r % 8;
    int q = tid >> 6, e = tid & 63;
    int h = hg * 4 + q;
    __shared__ float tl[4][DD];
    tl[q][e] = ts[((s * BB + b) * HH + h) * DD + e];
    __syncthreads();
    const float* M = MW + (s * HH + h) * DD * DD;
    float acc = Mb[(s * HH + h) * DD + e];
    #pragma unroll 8
    for (int d = 0; d < DD; ++d) acc += tl[q][d] * M[d * DD + e];
    proj[((s * BB + b) * HH + h) * DD + e] = acc;
}

// =====================================================================
// K4: RWKV lid-layer update + groupnorm (512) + sm chunks C4
// =====================================================================
__global__ __launch_bounds__(256) void k4_rwkv(
    const float4* __restrict__ sm4, float4* __restrict__ out_sm4,
    const float* __restrict__ proj,
    const float* __restrict__ gn_gamma, const float* __restrict__ gn_beta,
    float* __restrict__ a_out, const int* __restrict__ lid_p)
{
    int blk = blockIdx.x, tid = threadIdx.x;
    int lid = *lid_p;
    if (blk >= 512) {
        sm_chunk(C1 + C2 + C3 + blk - 512, lid,
                 (const nt4*)sm4, (nt4*)out_sm4, tid);
        return;
    }
    int b = blk / HH, h = blk % HH;
    long base4 = (long)(lid * BB * HH + blk) * (DD * DD / 4);
    int j = tid & 63, q = tid >> 6;
    const float* P = proj + (b * HH + h) * DD + j;
    float kv   = P[0 * BE];
    float rv   = P[1 * BE];
    float wraw = P[2 * BE];
    float vv   = P[3 * BE];
    float uv   = P[4 * BE];
    float wv = expf(-expf(wraw));
    float vr = vv * rv;
    #pragma unroll
    for (int o = 32; o; o >>= 1) vr += __shfl_xor(vr, o);
    __shared__ float rw[DD];
    const float* S = (const float*)(sm4 + base4);
    float* NS = (float*)(out_sm4 + base4);
    for (int ii = 0; ii < 16; ii += 4) {
        int i0 = q * 16 + ii;
        float sv[4], kk[4], ww[4], uu[4], pp[4];
        #pragma unroll
        for (int t = 0; t < 4; ++t) {
            sv[t] = S[(i0 + t) * DD + j];
            kk[t] = __shfl(kv, i0 + t);
            ww[t] = __shfl(wv, i0 + t);
            uu[t] = __shfl(uv, i0 + t);
        }
        #pragma unroll
        for (int t = 0; t < 4; ++t) {
            NS[(i0 + t) * DD + j] = ww[t] * sv[t] + kk[t] * vv;
            pp[t] = sv[t] * rv;
        }
        #pragma unroll
        for (int o = 32; o; o >>= 1) {
            #pragma unroll
            for (int t = 0; t < 4; ++t) pp[t] += __shfl_xor(pp[t], o);
        }
        if (j == 0) {
            #pragma unroll
            for (int t = 0; t < 4; ++t) rw[i0 + t] = kk[t] * uu[t] * vr + pp[t];
        }
    }
    __syncthreads();
    if (tid < DD) {
        float xv = rw[tid];
        float m = xv;
        #pragma unroll
        for (int o = 32; o; o >>= 1) m += __shfl_xor(m, o);
        m *= (1.f / 64.f);
        float d = xv - m;
        float var = d * d;
        #pragma unroll
        for (int o = 32; o; o >>= 1) var += __shfl_xor(var, o);
        var *= (1.f / 64.f);
        float normed = d * rsqrtf(var + GN_EPS);
        int e = h * DD + tid;
        a_out[b * EE + e] = normed * gn_gamma[e] + gn_beta[e];
    }
}

// =====================================================================
// K5: out GEMV with fused silu gating (256) + sm chunks C5 (last)
// =====================================================================
__global__ __launch_bounds__(256) void k5_out(
    const float* __restrict__ a, const float* __restrict__ g,
    const float* __restrict__ out_W, float* __restrict__ out_tm,
    const nt4* __restrict__ sm4, nt4* __restrict__ out_sm4,
    const int* __restrict__ lid_p)
{
    int blk = blockIdx.x, tid = threadIdx.x;
    if (blk < 256) { mm_block<true>(blk, a, g, out_W, out_tm, tid); return; }
    int lid = *lid_p;
    sm_chunk(C1 + C2 + C3 + C4 + blk - 256, lid, sm4, out_sm4, tid);
}

extern "C" void kernel_launch(void* const* d_in, const int* in_sizes, int n_in,
                              void* d_out, int out_size, void* d_ws, size_t ws_size,
                              hipStream_t stream) {
    const float* inputs   = (const float*)d_in[0];
    const float* state    = (const float*)d_in[1];
    const float* sm       = (const float*)d_in[2];
    const float* mus      = (const float*)d_in[3];
    const float* lambdas  = (const float*)d_in[4];
    const float* Aw       = (const float*)d_in[5];
    const float* Ab       = (const float*)d_in[6];
    const float* Bw       = (const float*)d_in[7];
    const float* Bb       = (const float*)d_in[8];
    const float* MW       = (const float*)d_in[9];
    const float* Mb       = (const float*)d_in[10];
    const float* gate_mu  = (const float*)d_in[11];
    const float* gate_W   = (const float*)d_in[12];
    const float* gate_b   = (const float*)d_in[13];
    const float* gn_gamma = (const float*)d_in[14];
    const float* gn_beta  = (const float*)d_in[15];
    const float* out_W    = (const float*)d_in[16];
    const float* out_b    = (const float*)d_in[17];
    const int*   lid      = (const int*)d_in[18];

    float* out_tm    = (float*)d_out;
    float* out_state = out_tm + BE;
    float* out_sm    = out_state + STATE_N;

    float* ws   = (float*)d_ws;
    float* ts   = ws;                       // NB*BE
    float* proj = ts + NB * BE;             // NB*BE
    float* hdn  = proj + NB * BE;           // NB*BB*TSH
    float* gx   = hdn + NB * BB * TSH;      // BE
    float* g    = gx + BE;                  // BE
    float* a    = g + BE;                   // BE

    k1_hdn<<<1232 + C1, 256, 0, stream>>>(inputs, state, mus, Aw, Ab, hdn,
        (const nt4*)state, (const float4*)inputs, (nt4*)out_state,
        out_tm, g, out_b, gate_b, gate_mu, gx,
        (const nt4*)sm, (nt4*)out_sm, lid);
    k2_ts<<<640 + C2, 256, 0, stream>>>(inputs, state, lambdas, Bw, Bb, hdn,
        ts, (const nt4*)sm, (nt4*)out_sm, lid);
    k3_proj<<<896 + C3, 256, 0, stream>>>(ts, MW, Mb, proj, gx, gate_W, g,
        (const nt4*)sm, (nt4*)out_sm, lid);
    k4_rwkv<<<512 + C4, 256, 0, stream>>>((const float4*)sm, (float4*)out_sm,
        proj, gn_gamma, gn_beta, a, lid);
    k5_out<<<256 + C5, 256, 0, stream>>>(a, g, out_W, out_tm,
        (const nt4*)sm, (nt4*)out_sm, lid);
}

// Round 5
// 429.095 us; speedup vs baseline: 1.0965x; 1.0182x over previous
//
#include <hip/hip_runtime.h>
#include <math.h>

#define NL 24
#define BB 16
#define HH 32
#define DD 64
#define EE 2048
#define TSH 32
#define NB 5
#define BE (BB*EE)            /* 32768  */
#define STATE_N (NL*BB*EE)    /* 786432 */
#define GN_EPS 1e-3f

/* 23 non-lid layers x 512 chunks of 16KB = 11776 sm passthrough chunks */
#define NCH 11776
#define C1 3300
#define C2 3200
#define C3 3200
#define C4 2076

typedef float nt4 __attribute__((ext_vector_type(4)));

// ---- one 16KB head-chunk of the 23-layer sm passthrough copy (nontemporal) ----
__device__ __forceinline__ void sm_chunk(int c, int lid, const nt4* __restrict__ sm4,
                                         nt4* __restrict__ out4, int tid) {
    int l = c >> 9, rr = c & 511;
    int ls = l + (l >= lid);
    const nt4* src = sm4 + (long)(ls * 512 + rr) * 1024;
    nt4*       dst = out4 + (long)(ls * 512 + rr) * 1024;
    #pragma unroll
    for (int p = 0; p < 4; ++p) {
        nt4 v = __builtin_nontemporal_load(&src[p * 256 + tid]);
        __builtin_nontemporal_store(v, &dst[p * 256 + tid]);
    }
}

// =====================================================================
// K1: hdn (80) + state copy (768) + aux bias/gx (384) + sm chunks C1
// =====================================================================
__global__ __launch_bounds__(256) void k1_hdn(
    const float* __restrict__ inputs, const float* __restrict__ state,
    const float* __restrict__ mus, const float* __restrict__ Aw,
    const float* __restrict__ Ab, float* __restrict__ hdn,
    const nt4* __restrict__ state4, const float4* __restrict__ inputs4,
    nt4* __restrict__ out_state4, float* __restrict__ out_tm,
    float* __restrict__ g, const float* __restrict__ out_b,
    const float* __restrict__ gate_b, const float* __restrict__ gate_mu,
    float* __restrict__ gx,
    const nt4* __restrict__ sm4, nt4* __restrict__ out_sm4,
    const int* __restrict__ lid_p)
{
    int blk = blockIdx.x, tid = threadIdx.x;
    int lid = *lid_p;
    if (blk >= 1232) {                          // sm copy chunks [0, C1)
        sm_chunk(blk - 1232, lid, sm4, out_sm4, tid);
        return;
    }
    if (blk >= 848) {                           // aux: out_tm/g bias + gx (98304)
        int idx = (blk - 848) * 256 + tid;
        if (idx < BE) out_tm[idx] = out_b[idx & (EE - 1)];
        else if (idx < 2 * BE) g[idx - BE] = gate_b[(idx - BE) & (EE - 1)];
        else {
            int r = idx - 2 * BE;
            float xv = inputs[r];
            float lxv = state[lid * BE + r];
            float gm = gate_mu[r & (EE - 1)];
            gx[r] = xv * gm + lxv * (1.f - gm);
        }
        return;
    }
    if (blk >= 80) {                            // state copy (196608 float4)
        int i = (blk - 80) * 256 + tid;
        int lo = lid * (BE / 4);
        if (i >= lo && i < lo + BE / 4) {
            float4 v = inputs4[i - lo];
            nt4 w = { v.x, v.y, v.z, v.w };
            __builtin_nontemporal_store(w, &out_state4[i]);
        } else {
            nt4 v = __builtin_nontemporal_load(&state4[i]);
            __builtin_nontemporal_store(v, &out_state4[i]);
        }
        return;
    }
    // ---- hdn for one (s,b) ----
    int s = blk / BB, b = blk % BB;
    __shared__ float li[EE];
    const float* x  = inputs + b * EE;
    const float* lx = state + lid * BE + b * EE;
    const float* mu = mus + s * EE;
    for (int e = tid; e < EE; e += 256) {
        float xv = x[e];
        li[e] = xv + (xv - lx[e]) * mu[e];
    }
    __syncthreads();
    int h = tid & 31, part = tid >> 5;          // 8 parts x 256 elems
    const float* A = Aw + s * EE * TSH;
    float acc = 0.f;
    int e0 = part * 256;
    #pragma unroll 8
    for (int e = e0; e < e0 + 256; ++e) acc += li[e] * A[e * TSH + h];
    __shared__ float red[32][9];
    red[h][part] = acc;
    __syncthreads();
    if (tid < 32) {
        float sum = Ab[s * TSH + tid];
        #pragma unroll
        for (int p = 0; p < 8; ++p) sum += red[tid][p];
        hdn[(s * BB + b) * TSH + tid] = tanhf(sum);
    }
}

// ---- GEMV block (256 thr): out[b,e] += sum_k A[b,k]*W[k,e]; LDS-staged A ----
template <bool SILU>
__device__ __forceinline__ void mm_block(
    int t, const float* __restrict__ Arows, const float* __restrict__ Grows,
    const float* __restrict__ W, float* __restrict__ out, int tid)
{
    int et = t & 7, kc = t >> 3;
    int e = et * 256 + tid;
    int k0 = kc * 64;
    __shared__ float As[BB][64];
    for (int i = tid; i < BB * 64; i += 256) {
        int b = i >> 6, kk = i & 63;
        float av = Arows[b * EE + k0 + kk];
        if constexpr (SILU) {
            float gv = Grows[b * EE + k0 + kk];
            av *= gv / (1.f + expf(-gv));
        }
        As[b][kk] = av;
    }
    __syncthreads();
    float acc[BB];
    #pragma unroll
    for (int b = 0; b < BB; ++b) acc[b] = 0.f;
    #pragma unroll 8
    for (int kk = 0; kk < 64; ++kk) {
        float wv = W[(k0 + kk) * EE + e];
        #pragma unroll
        for (int b = 0; b < BB; ++b) acc[b] += As[b][kk] * wv;
    }
    #pragma unroll
    for (int b = 0; b < BB; ++b) atomicAdd(&out[b * EE + e], acc[b]);
}

// =====================================================================
// K2: fused ts+proj (640 blocks: s x b x 4-head group, ts kept in LDS)
//     + gate GEMV (256) + sm chunks C2
// =====================================================================
__global__ __launch_bounds__(256) void k2_tsproj(
    const float* __restrict__ inputs, const float* __restrict__ state,
    const float* __restrict__ lambdas, const float* __restrict__ Bw,
    const float* __restrict__ Bb, const float* __restrict__ hdn,
    const float* __restrict__ MW, const float* __restrict__ Mb,
    float* __restrict__ proj,
    const float* __restrict__ gx, const float* __restrict__ gate_W,
    float* __restrict__ g,
    const nt4* __restrict__ sm4, nt4* __restrict__ out_sm4,
    const int* __restrict__ lid_p)
{
    int blk = blockIdx.x, tid = threadIdx.x;
    if (blk >= 896) {                           // sm copy chunks [C1, C1+C2)
        int lid = *lid_p;
        sm_chunk(C1 + blk - 896, lid, sm4, out_sm4, tid);
        return;
    }
    if (blk >= 640) {                           // gate GEMV
        mm_block<false>(blk - 640, gx, nullptr, gate_W, g, tid);
        return;
    }
    int lid = *lid_p;
    // ---- block = (s, b, hg): e-range [hg*256, hg*256+256) = heads hg*4..+3 ----
    int s = blk / (BB * 8);
    int r = blk % (BB * 8);
    int b = r / 8, hg = r % 8;
    int e = hg * 256 + tid;                     // element within E for ts
    __shared__ float hl[TSH];
    __shared__ float tsl[256];
    if (tid < TSH) hl[tid] = hdn[(s * BB + b) * TSH + tid];
    __syncthreads();
    {
        int ge = b * EE + e;
        const float* Bp = Bw + s * TSH * EE + e;
        float acc = Bb[s * EE + e] + lambdas[s * EE + e];
        #pragma unroll
        for (int h = 0; h < TSH; ++h) acc += hl[h] * Bp[h * EE];
        float xv = inputs[ge];
        float lxv = state[lid * BE + ge];
        tsl[tid] = acc * (xv - lxv) + xv;
    }
    __syncthreads();
    // ---- per-head dense for the 4 heads covered by this e-range ----
    int q = tid >> 6, e2 = tid & 63;
    int h = hg * 4 + q;
    const float* M = MW + (s * HH + h) * DD * DD;
    const float* t = tsl + q * DD;
    float acc = Mb[(s * HH + h) * DD + e2];
    #pragma unroll 8
    for (int d = 0; d < DD; ++d) acc += t[d] * M[d * DD + e2];
    proj[((s * BB + b) * HH + h) * DD + e2] = acc;
}

// =====================================================================
// K3: RWKV lid-layer update + groupnorm (512) + sm chunks C3
// =====================================================================
__global__ __launch_bounds__(256) void k3_rwkv(
    const float4* __restrict__ sm4, float4* __restrict__ out_sm4,
    const float* __restrict__ proj,
    const float* __restrict__ gn_gamma, const float* __restrict__ gn_beta,
    float* __restrict__ a_out, const int* __restrict__ lid_p)
{
    int blk = blockIdx.x, tid = threadIdx.x;
    int lid = *lid_p;
    if (blk >= 512) {
        sm_chunk(C1 + C2 + blk - 512, lid,
                 (const nt4*)sm4, (nt4*)out_sm4, tid);
        return;
    }
    int b = blk / HH, h = blk % HH;
    long base4 = (long)(lid * BB * HH + blk) * (DD * DD / 4);
    int j = tid & 63, q = tid >> 6;
    const float* P = proj + (b * HH + h) * DD + j;
    float kv   = P[0 * BE];
    float rv   = P[1 * BE];
    float wraw = P[2 * BE];
    float vv   = P[3 * BE];
    float uv   = P[4 * BE];
    float wv = expf(-expf(wraw));
    float vr = vv * rv;
    #pragma unroll
    for (int o = 32; o; o >>= 1) vr += __shfl_xor(vr, o);
    __shared__ float rw[DD];
    const float* S = (const float*)(sm4 + base4);
    float* NS = (float*)(out_sm4 + base4);
    for (int ii = 0; ii < 16; ii += 4) {
        int i0 = q * 16 + ii;
        float sv[4], kk[4], ww[4], uu[4], pp[4];
        #pragma unroll
        for (int t = 0; t < 4; ++t) {
            sv[t] = S[(i0 + t) * DD + j];
            kk[t] = __shfl(kv, i0 + t);
            ww[t] = __shfl(wv, i0 + t);
            uu[t] = __shfl(uv, i0 + t);
        }
        #pragma unroll
        for (int t = 0; t < 4; ++t) {
            NS[(i0 + t) * DD + j] = ww[t] * sv[t] + kk[t] * vv;
            pp[t] = sv[t] * rv;
        }
        #pragma unroll
        for (int o = 32; o; o >>= 1) {
            #pragma unroll
            for (int t = 0; t < 4; ++t) pp[t] += __shfl_xor(pp[t], o);
        }
        if (j == 0) {
            #pragma unroll
            for (int t = 0; t < 4; ++t) rw[i0 + t] = kk[t] * uu[t] * vr + pp[t];
        }
    }
    __syncthreads();
    if (tid < DD) {
        float xv = rw[tid];
        float m = xv;
        #pragma unroll
        for (int o = 32; o; o >>= 1) m += __shfl_xor(m, o);
        m *= (1.f / 64.f);
        float d = xv - m;
        float var = d * d;
        #pragma unroll
        for (int o = 32; o; o >>= 1) var += __shfl_xor(var, o);
        var *= (1.f / 64.f);
        float normed = d * rsqrtf(var + GN_EPS);
        int e = h * DD + tid;
        a_out[b * EE + e] = normed * gn_gamma[e] + gn_beta[e];
    }
}

// =====================================================================
// K4: out GEMV with fused silu gating (256) + sm chunks C4 (last)
// =====================================================================
__global__ __launch_bounds__(256) void k4_out(
    const float* __restrict__ a, const float* __restrict__ g,
    const float* __restrict__ out_W, float* __restrict__ out_tm,
    const nt4* __restrict__ sm4, nt4* __restrict__ out_sm4,
    const int* __restrict__ lid_p)
{
    int blk = blockIdx.x, tid = threadIdx.x;
    if (blk < 256) { mm_block<true>(blk, a, g, out_W, out_tm, tid); return; }
    int lid = *lid_p;
    sm_chunk(C1 + C2 + C3 + blk - 256, lid, sm4, out_sm4, tid);
}

extern "C" void kernel_launch(void* const* d_in, const int* in_sizes, int n_in,
                              void* d_out, int out_size, void* d_ws, size_t ws_size,
                              hipStream_t stream) {
    const float* inputs   = (const float*)d_in[0];
    const float* state    = (const float*)d_in[1];
    const float* sm       = (const float*)d_in[2];
    const float* mus      = (const float*)d_in[3];
    const float* lambdas  = (const float*)d_in[4];
    const float* Aw       = (const float*)d_in[5];
    const float* Ab       = (const float*)d_in[6];
    const float* Bw       = (const float*)d_in[7];
    const float* Bb       = (const float*)d_in[8];
    const float* MW       = (const float*)d_in[9];
    const float* Mb       = (const float*)d_in[10];
    const float* gate_mu  = (const float*)d_in[11];
    const float* gate_W   = (const float*)d_in[12];
    const float* gate_b   = (const float*)d_in[13];
    const float* gn_gamma = (const float*)d_in[14];
    const float* gn_beta  = (const float*)d_in[15];
    const float* out_W    = (const float*)d_in[16];
    const float* out_b    = (const float*)d_in[17];
    const int*   lid      = (const int*)d_in[18];

    float* out_tm    = (float*)d_out;
    float* out_state = out_tm + BE;
    float* out_sm    = out_state + STATE_N;

    float* ws   = (float*)d_ws;
    float* proj = ws;                       // NB*BE
    float* hdn  = proj + NB * BE;           // NB*BB*TSH
    float* gx   = hdn + NB * BB * TSH;      // BE
    float* g    = gx + BE;                  // BE
    float* a    = g + BE;                   // BE

    k1_hdn<<<1232 + C1, 256, 0, stream>>>(inputs, state, mus, Aw, Ab, hdn,
        (const nt4*)state, (const float4*)inputs, (nt4*)out_state,
        out_tm, g, out_b, gate_b, gate_mu, gx,
        (const nt4*)sm, (nt4*)out_sm, lid);
    k2_tsproj<<<896 + C2, 256, 0, stream>>>(inputs, state, lambdas, Bw, Bb, hdn,
        MW, Mb, proj, gx, gate_W, g,
        (const nt4*)sm, (nt4*)out_sm, lid);
    k3_rwkv<<<512 + C3, 256, 0, stream>>>((const float4*)sm, (float4*)out_sm,
        proj, gn_gamma, gn_beta, a, lid);
    k4_out<<<256 + C4, 256, 0, stream>>>(a, g, out_W, out_tm,
        (const nt4*)sm, (nt4*)out_sm, lid);
}

// Round 6
// 417.820 us; speedup vs baseline: 1.1261x; 1.0270x over previous
//
#include <hip/hip_runtime.h>
#include <math.h>

#define NL 24
#define BB 16
#define HH 32
#define DD 64
#define EE 2048
#define TSH 32
#define NB 5
#define BE (BB*EE)            /* 32768  */
#define STATE_N (NL*BB*EE)    /* 786432 */
#define GN_EPS 1e-3f

/* 23 non-lid layers x 512 chunks of 16KB = 11776 sm passthrough chunks */
#define NCH 11776
#define CA 4600
#define CB 4600
#define CC 2576

typedef float nt4 __attribute__((ext_vector_type(4)));

// ---- one 16KB head-chunk of the 23-layer sm passthrough copy (nontemporal) ----
__device__ __forceinline__ void sm_chunk(int c, int lid, const nt4* __restrict__ sm4,
                                         nt4* __restrict__ out4, int tid) {
    int l = c >> 9, rr = c & 511;
    int ls = l + (l >= lid);
    const nt4* src = sm4 + (long)(ls * 512 + rr) * 1024;
    nt4*       dst = out4 + (long)(ls * 512 + rr) * 1024;
    #pragma unroll
    for (int p = 0; p < 4; ++p) {
        nt4 v = __builtin_nontemporal_load(&src[p * 256 + tid]);
        __builtin_nontemporal_store(v, &dst[p * 256 + tid]);
    }
}

// =====================================================================
// KA: fused hdn+ts+proj (640 blocks: s x b x 4-head group; hdn recomputed
//     in-block, Aw L2-resident) + state copy (768) + bias inits (256)
//     + sm chunks CA
// =====================================================================
__global__ __launch_bounds__(256) void kA_branch(
    const float* __restrict__ inputs, const float* __restrict__ state,
    const float* __restrict__ mus, const float* __restrict__ Aw,
    const float* __restrict__ Ab, const float* __restrict__ lambdas,
    const float* __restrict__ Bw, const float* __restrict__ Bb,
    const float* __restrict__ MW, const float* __restrict__ Mb,
    float* __restrict__ proj,
    const nt4* __restrict__ state4, const float4* __restrict__ inputs4,
    nt4* __restrict__ out_state4, float* __restrict__ out_tm,
    float* __restrict__ g, const float* __restrict__ out_b,
    const float* __restrict__ gate_b,
    const nt4* __restrict__ sm4, nt4* __restrict__ out_sm4,
    const int* __restrict__ lid_p)
{
    int blk = blockIdx.x, tid = threadIdx.x;
    int lid = *lid_p;
    if (blk >= 1664) {                          // sm copy chunks [0, CA)
        sm_chunk(blk - 1664, lid, sm4, out_sm4, tid);
        return;
    }
    if (blk >= 1408) {                          // bias inits (65536 elems)
        int idx = (blk - 1408) * 256 + tid;
        if (idx < BE) out_tm[idx] = out_b[idx & (EE - 1)];
        else g[idx - BE] = gate_b[(idx - BE) & (EE - 1)];
        return;
    }
    if (blk >= 640) {                           // state copy (196608 float4)
        int i = (blk - 640) * 256 + tid;
        int lo = lid * (BE / 4);
        if (i >= lo && i < lo + BE / 4) {
            float4 v = inputs4[i - lo];
            nt4 w = { v.x, v.y, v.z, v.w };
            __builtin_nontemporal_store(w, &out_state4[i]);
        } else {
            nt4 v = __builtin_nontemporal_load(&state4[i]);
            __builtin_nontemporal_store(v, &out_state4[i]);
        }
        return;
    }
    // ---- block = (s, b, hg): e-range [hg*256, +256) = heads hg*4..hg*4+3 ----
    int s = blk / (BB * 8);
    int r = blk % (BB * 8);
    int b = r / 8, hg = r % 8;
    __shared__ float li[EE];                    // 8 KB
    __shared__ float red[TSH][9];
    __shared__ float hdnl[TSH];
    __shared__ float tsl[256];
    const float* x  = inputs + b * EE;
    const float* lx = state + lid * BE + b * EE;
    const float* mu = mus + s * EE;
    for (int e = tid; e < EE; e += 256) {
        float xv = x[e];
        li[e] = xv + (xv - lx[e]) * mu[e];
    }
    __syncthreads();
    {   // hdn partials: 8 parts x 256 elems, 32 h-lanes each (k1's body)
        int h = tid & 31, part = tid >> 5;
        const float* A = Aw + s * EE * TSH;
        float acc = 0.f;
        int e0 = part * 256;
        #pragma unroll 8
        for (int e = e0; e < e0 + 256; ++e) acc += li[e] * A[e * TSH + h];
        red[h][part] = acc;
    }
    __syncthreads();
    if (tid < TSH) {
        float sum = Ab[s * TSH + tid];
        #pragma unroll
        for (int p = 0; p < 8; ++p) sum += red[tid][p];
        hdnl[tid] = tanhf(sum);
    }
    __syncthreads();
    {   // ts for this block's 256-wide e-range (kept in LDS)
        int e = hg * 256 + tid;
        const float* Bp = Bw + s * TSH * EE + e;
        float acc = Bb[s * EE + e] + lambdas[s * EE + e];
        #pragma unroll
        for (int h = 0; h < TSH; ++h) acc += hdnl[h] * Bp[h * EE];
        float xv = x[e];
        float lxv = lx[e];
        tsl[tid] = acc * (xv - lxv) + xv;
    }
    __syncthreads();
    // ---- per-head dense for the 4 heads covered by this e-range ----
    int q = tid >> 6, e2 = tid & 63;
    int h = hg * 4 + q;
    const float* M = MW + (s * HH + h) * DD * DD;
    const float* t = tsl + q * DD;
    float acc = Mb[(s * HH + h) * DD + e2];
    #pragma unroll 8
    for (int d = 0; d < DD; ++d) acc += t[d] * M[d * DD + e2];
    proj[((s * BB + b) * HH + h) * DD + e2] = acc;
}

// ---- GEMV block (256 thr): out[b,e] += sum_k A[b,k]*W[k,e]; LDS-staged A ----
// MODE 1: staged = A1 * silu(A2)
// MODE 2: staged = A1*gm + A2*(1-gm)   (gx computed inline; A2 pre-offset state)
template <int MODE>
__device__ __forceinline__ void mm_block(
    int t, const float* __restrict__ A1, const float* __restrict__ A2,
    const float* __restrict__ gmu,
    const float* __restrict__ W, float* __restrict__ out, int tid)
{
    int et = t & 7, kc = t >> 3;
    int e = et * 256 + tid;
    int k0 = kc * 64;
    __shared__ float As[BB][64];
    for (int i = tid; i < BB * 64; i += 256) {
        int b = i >> 6, kk = i & 63;
        int idx = b * EE + k0 + kk;
        float av;
        if constexpr (MODE == 1) {
            float gv = A2[idx];
            av = A1[idx] * (gv / (1.f + expf(-gv)));
        } else {
            float gm = gmu[k0 + kk];
            av = A1[idx] * gm + A2[idx] * (1.f - gm);
        }
        As[b][kk] = av;
    }
    __syncthreads();
    float acc[BB];
    #pragma unroll
    for (int b = 0; b < BB; ++b) acc[b] = 0.f;
    #pragma unroll 8
    for (int kk = 0; kk < 64; ++kk) {
        float wv = W[(k0 + kk) * EE + e];
        #pragma unroll
        for (int b = 0; b < BB; ++b) acc[b] += As[b][kk] * wv;
    }
    #pragma unroll
    for (int b = 0; b < BB; ++b) atomicAdd(&out[b * EE + e], acc[b]);
}

// =====================================================================
// KB: RWKV lid-layer update + groupnorm (512) + gate GEMV w/ inline gx
//     (256) + sm chunks CB
// =====================================================================
__global__ __launch_bounds__(256) void kB_rwkv(
    const float4* __restrict__ sm4, float4* __restrict__ out_sm4,
    const float* __restrict__ proj,
    const float* __restrict__ gn_gamma, const float* __restrict__ gn_beta,
    float* __restrict__ a_out,
    const float* __restrict__ inputs, const float* __restrict__ state,
    const float* __restrict__ gate_mu, const float* __restrict__ gate_W,
    float* __restrict__ g, const int* __restrict__ lid_p)
{
    int blk = blockIdx.x, tid = threadIdx.x;
    int lid = *lid_p;
    if (blk >= 768) {                           // sm copy chunks [CA, CA+CB)
        sm_chunk(CA + blk - 768, lid, (const nt4*)sm4, (nt4*)out_sm4, tid);
        return;
    }
    if (blk >= 512) {                           // gate GEMV, gx inline
        mm_block<2>(blk - 512, inputs, state + lid * BE, gate_mu, gate_W, g, tid);
        return;
    }
    int b = blk / HH, h = blk % HH;
    long base4 = (long)(lid * BB * HH + blk) * (DD * DD / 4);
    int j = tid & 63, q = tid >> 6;
    const float* P = proj + (b * HH + h) * DD + j;
    float kv   = P[0 * BE];
    float rv   = P[1 * BE];
    float wraw = P[2 * BE];
    float vv   = P[3 * BE];
    float uv   = P[4 * BE];
    float wv = expf(-expf(wraw));
    float vr = vv * rv;
    #pragma unroll
    for (int o = 32; o; o >>= 1) vr += __shfl_xor(vr, o);
    __shared__ float rw[DD];
    const float* S = (const float*)(sm4 + base4);
    float* NS = (float*)(out_sm4 + base4);
    for (int ii = 0; ii < 16; ii += 4) {
        int i0 = q * 16 + ii;
        float sv[4], kk[4], ww[4], uu[4], pp[4];
        #pragma unroll
        for (int t = 0; t < 4; ++t) {
            sv[t] = S[(i0 + t) * DD + j];
            kk[t] = __shfl(kv, i0 + t);
            ww[t] = __shfl(wv, i0 + t);
            uu[t] = __shfl(uv, i0 + t);
        }
        #pragma unroll
        for (int t = 0; t < 4; ++t) {
            NS[(i0 + t) * DD + j] = ww[t] * sv[t] + kk[t] * vv;
            pp[t] = sv[t] * rv;
        }
        #pragma unroll
        for (int o = 32; o; o >>= 1) {
            #pragma unroll
            for (int t = 0; t < 4; ++t) pp[t] += __shfl_xor(pp[t], o);
        }
        if (j == 0) {
            #pragma unroll
            for (int t = 0; t < 4; ++t) rw[i0 + t] = kk[t] * uu[t] * vr + pp[t];
        }
    }
    __syncthreads();
    if (tid < DD) {
        float xv = rw[tid];
        float m = xv;
        #pragma unroll
        for (int o = 32; o; o >>= 1) m += __shfl_xor(m, o);
        m *= (1.f / 64.f);
        float d = xv - m;
        float var = d * d;
        #pragma unroll
        for (int o = 32; o; o >>= 1) var += __shfl_xor(var, o);
        var *= (1.f / 64.f);
        float normed = d * rsqrtf(var + GN_EPS);
        int e = h * DD + tid;
        a_out[b * EE + e] = normed * gn_gamma[e] + gn_beta[e];
    }
}

// =====================================================================
// KC: out GEMV with fused silu gating (256) + sm chunks CC (last)
// =====================================================================
__global__ __launch_bounds__(256) void kC_out(
    const float* __restrict__ a, const float* __restrict__ g,
    const float* __restrict__ out_W, float* __restrict__ out_tm,
    const nt4* __restrict__ sm4, nt4* __restrict__ out_sm4,
    const int* __restrict__ lid_p)
{
    int blk = blockIdx.x, tid = threadIdx.x;
    if (blk < 256) { mm_block<1>(blk, a, g, nullptr, out_W, out_tm, tid); return; }
    int lid = *lid_p;
    sm_chunk(CA + CB + blk - 256, lid, sm4, out_sm4, tid);
}

extern "C" void kernel_launch(void* const* d_in, const int* in_sizes, int n_in,
                              void* d_out, int out_size, void* d_ws, size_t ws_size,
                              hipStream_t stream) {
    const float* inputs   = (const float*)d_in[0];
    const float* state    = (const float*)d_in[1];
    const float* sm       = (const float*)d_in[2];
    const float* mus      = (const float*)d_in[3];
    const float* lambdas  = (const float*)d_in[4];
    const float* Aw       = (const float*)d_in[5];
    const float* Ab       = (const float*)d_in[6];
    const float* Bw       = (const float*)d_in[7];
    const float* Bb       = (const float*)d_in[8];
    const float* MW       = (const float*)d_in[9];
    const float* Mb       = (const float*)d_in[10];
    const float* gate_mu  = (const float*)d_in[11];
    const float* gate_W   = (const float*)d_in[12];
    const float* gate_b   = (const float*)d_in[13];
    const float* gn_gamma = (const float*)d_in[14];
    const float* gn_beta  = (const float*)d_in[15];
    const float* out_W    = (const float*)d_in[16];
    const float* out_b    = (const float*)d_in[17];
    const int*   lid      = (const int*)d_in[18];

    float* out_tm    = (float*)d_out;
    float* out_state = out_tm + BE;
    float* out_sm    = out_state + STATE_N;

    float* ws   = (float*)d_ws;
    float* proj = ws;                       // NB*BE
    float* g    = proj + NB * BE;           // BE
    float* a    = g + BE;                   // BE

    kA_branch<<<1664 + CA, 256, 0, stream>>>(inputs, state, mus, Aw, Ab,
        lambdas, Bw, Bb, MW, Mb, proj,
        (const nt4*)state, (const float4*)inputs, (nt4*)out_state,
        out_tm, g, out_b, gate_b,
        (const nt4*)sm, (nt4*)out_sm, lid);
    kB_rwkv<<<768 + CB, 256, 0, stream>>>((const float4*)sm, (float4*)out_sm,
        proj, gn_gamma, gn_beta, a, inputs, state, gate_mu, gate_W, g, lid);
    kC_out<<<256 + CC, 256, 0, stream>>>(a, g, out_W, out_tm,
        (const nt4*)sm, (nt4*)out_sm, lid);
}